// Round 12
// baseline (412.768 us; speedup 1.0000x reference)
//
#include <hip/hip_runtime.h>

// ICNN_net_1503238553972 — round 12: heterogeneous fused kernel, 6 blocks/CU.
// vs R11: fhat body shrunk to 64 rows (16 KB H, R6's wave=32-out-ch layout)
// so fused LDS = 24 KB -> 6 blocks/CU (24 waves, 75% cap). Block mix 1:1
// (7813 fhat + 7813 vnet, blockIdx&1). launch_bounds stays (256,4): actual
// VGPR ~64 lets HW schedule 6 blocks; tightening the bound causes spill (R7/R8).
// vnet writes (g0,g1,V) to g_grad; combine kernel does the epilogue.

typedef _Float16 v2h __attribute__((ext_vector_type(2)));
typedef _Float16 v4h __attribute__((ext_vector_type(4)));
typedef _Float16 v8h __attribute__((ext_vector_type(8)));
typedef float    v4f __attribute__((ext_vector_type(4)));

#define NPTS 500000
#define FH_BLK  ((NPTS + 63) / 64)     // 7813
#define VN_BLK  ((NPTS + 63) / 64)     // 7813
#define FUSED_GRID (FH_BLK + VN_BLK)   // 15626

// offsets in halves inside g_w16
#define OFF_FW    0               // f2..f5: L*16384, [o*128+k]
#define OFF_V2Z   65536           // [j*64+k]
#define OFF_V3Z   69632
#define OFF_V2ZT  73728           // [k*64+j]
#define OFF_V3ZT  77824
#define OFF_VL1T  81920           // [c*64+j]
#define OFF_V2XT  82048
#define OFF_V3XT  82176
#define OFF_VFZ   82304           // [64]
#define OFF_FFW   82368           // [c*128+k]
#define OFF_F1W   82624           // [oc*2+c]
#define W16_DATA  82880
#define W16_TOTAL (W16_DATA + 2048)   // zero pad: junk A-rows stay in-bounds

__device__ __align__(16) _Float16 g_w16[W16_TOTAL];
__device__ __align__(16) float    g_fh[NPTS * 2];   // f_hat per row (fp32)
__device__ __align__(16) float4   g_grad[NPTS];     // (g0, g1, V, pad)

#if defined(__has_builtin)
#if __has_builtin(__builtin_amdgcn_fdot2)
#define FDOT2(a,b,c) __builtin_amdgcn_fdot2((a),(b),(c),false)
#endif
#endif
#ifndef FDOT2
__device__ __forceinline__ float fdot2_fb(v2h a, v2h b, float c){
  return fmaf((float)a.x, (float)b.x, fmaf((float)a.y, (float)b.y, c));
}
#define FDOT2(a,b,c) fdot2_fb((a),(b),(c))
#endif

__device__ __forceinline__ float srelu(float x){
  float c = fminf(fmaxf(x, 0.f), 1.f);
  return c * fmaf(-0.5f, c, x);
}
__device__ __forceinline__ float sreluD(float x){
  return fminf(fmaxf(x, 0.f), 1.f);
}
__device__ __forceinline__ float lrelu(float x){
  return fmaxf(x, 0.01f * x);
}
__device__ __forceinline__ float sreluD_from_z(float z){
  return fminf(sqrtf(2.f * z), 1.f);
}
__device__ __forceinline__ float dot8(v8h a, v8h b, float s){
  const v2h* ap = (const v2h*)&a;
  const v2h* bp = (const v2h*)&b;
  s = FDOT2(ap[0], bp[0], s);
  s = FDOT2(ap[1], bp[1], s);
  s = FDOT2(ap[2], bp[2], s);
  s = FDOT2(ap[3], bp[3], s);
  return s;
}

// ---------------- prep: fp32 weights -> f16 layouts (+zero pad) ----------------
__global__ __launch_bounds__(256) void prep_kernel(
  const float* __restrict__ f2w, const float* __restrict__ f3w,
  const float* __restrict__ f4w, const float* __restrict__ f5w,
  const float* __restrict__ V2z, const float* __restrict__ V3z,
  const float* __restrict__ Vl1, const float* __restrict__ V2x,
  const float* __restrict__ V3x, const float* __restrict__ Vfz,
  const float* __restrict__ ffw, const float* __restrict__ f1w)
{
  const int i = blockIdx.x * 256 + threadIdx.x;
  if (i >= W16_TOTAL) return;
  if (i >= W16_DATA){ g_w16[i] = (_Float16)0.f; return; }
  float v;
  if (i < 65536){
    const float* W[4] = {f2w, f3w, f4w, f5w};
    v = W[i >> 14][i & 16383];
  } else if (i < 69632)  v = V2z[i - 65536];
  else if (i < 73728)    v = V3z[i - 69632];
  else if (i < 77824){ int r = i - 73728; v = V2z[(r & 63)*64 + (r >> 6)]; }
  else if (i < 81920){ int r = i - 77824; v = V3z[(r & 63)*64 + (r >> 6)]; }
  else if (i < 82048){ int r = i - 81920; v = Vl1[(r & 63)*2 + (r >> 6)]; }
  else if (i < 82176){ int r = i - 82048; v = V2x[(r & 63)*2 + (r >> 6)]; }
  else if (i < 82304){ int r = i - 82176; v = V3x[(r & 63)*2 + (r >> 6)]; }
  else if (i < 82368)    v = Vfz[i - 82304];
  else if (i < 82624)    v = ffw[i - 82368];
  else                   v = f1w[i - 82624];
  g_w16[i] = (_Float16)v;
}

// ================= fhat block body: 256 thr, 64 rows (16 KB H) =================
// layer: wave w owns out-ch w*32..w*32+31 for all 64 rows (acc[2][4]).
__device__ __forceinline__ void fh_layer64(_Float16* H,
    const _Float16* __restrict__ Wl, const float* __restrict__ Bp,
    int w, int lm, int q)
{
  v4f acc[2][4];
#pragma unroll
  for (int mt = 0; mt < 2; ++mt)
#pragma unroll
    for (int nt = 0; nt < 4; ++nt) acc[mt][nt] = (v4f){0.f,0.f,0.f,0.f};

#pragma unroll
  for (int kt = 0; kt < 4; ++kt){
    const int sw = ((kt*4 + q) ^ lm) << 3;
    v8h A0 = *(const v8h*)(Wl + (w*32      + lm)*128 + kt*32 + q*8);
    v8h A1 = *(const v8h*)(Wl + (w*32 + 16 + lm)*128 + kt*32 + q*8);
    v8h B0 = *(const v8h*)(H + (     lm)*128 + sw);
    v8h B1 = *(const v8h*)(H + (16 + lm)*128 + sw);
    v8h B2 = *(const v8h*)(H + (32 + lm)*128 + sw);
    v8h B3 = *(const v8h*)(H + (48 + lm)*128 + sw);
    acc[0][0] = __builtin_amdgcn_mfma_f32_16x16x32_f16(A0, B0, acc[0][0], 0,0,0);
    acc[0][1] = __builtin_amdgcn_mfma_f32_16x16x32_f16(A0, B1, acc[0][1], 0,0,0);
    acc[0][2] = __builtin_amdgcn_mfma_f32_16x16x32_f16(A0, B2, acc[0][2], 0,0,0);
    acc[0][3] = __builtin_amdgcn_mfma_f32_16x16x32_f16(A0, B3, acc[0][3], 0,0,0);
    acc[1][0] = __builtin_amdgcn_mfma_f32_16x16x32_f16(A1, B0, acc[1][0], 0,0,0);
    acc[1][1] = __builtin_amdgcn_mfma_f32_16x16x32_f16(A1, B1, acc[1][1], 0,0,0);
    acc[1][2] = __builtin_amdgcn_mfma_f32_16x16x32_f16(A1, B2, acc[1][2], 0,0,0);
    acc[1][3] = __builtin_amdgcn_mfma_f32_16x16x32_f16(A1, B3, acc[1][3], 0,0,0);
  }
  __syncthreads();   // all waves' B reads complete before any write
#pragma unroll
  for (int mt = 0; mt < 2; ++mt){
    const int o0 = w*32 + mt*16 + q*4;
    const v4f bv = *(const v4f*)(Bp + o0);
    const int coff = (((o0 >> 3) ^ lm) << 3) + (o0 & 7);
#pragma unroll
    for (int nt = 0; nt < 4; ++nt){
      v4h hv;
      hv[0] = (_Float16)lrelu(acc[mt][nt][0] + bv[0]);
      hv[1] = (_Float16)lrelu(acc[mt][nt][1] + bv[1]);
      hv[2] = (_Float16)lrelu(acc[mt][nt][2] + bv[2]);
      hv[3] = (_Float16)lrelu(acc[mt][nt][3] + bv[3]);
      *(v4h*)(H + (nt*16 + lm)*128 + coff) = hv;
    }
  }
  __syncthreads();   // writes visible before next layer's reads
}

__device__ __forceinline__ void fhat_body(int b, _Float16* H,
  const float* __restrict__ X,
  const float* __restrict__ f1b, const float* __restrict__ f2b,
  const float* __restrict__ f3b, const float* __restrict__ f4b,
  const float* __restrict__ f5b, const float* __restrict__ ffb)
{
  const int t  = threadIdx.x;
  const int w  = t >> 6;
  const int l  = t & 63;
  const int lm = l & 15;
  const int q  = l >> 4;

  // layer1 (K=2, dot2): thread = (rows tx+16i, col-chunk ty)
  {
    const int tx = t & 15, ty = t >> 4;
    v2h wv[8]; float bb[8];
#pragma unroll
    for (int j = 0; j < 8; ++j){
      wv[j] = *(const v2h*)(g_w16 + OFF_F1W + (ty*8 + j)*2);
      bb[j] = f1b[ty*8 + j];
    }
#pragma unroll
    for (int i = 0; i < 4; ++i){
      const int r = tx + 16*i;
      int g = b*64 + r; if (g > NPTS-1) g = NPTS-1;
      const float2 xv = *(const float2*)(X + g*2);
      v2h xh; xh.x = (_Float16)xv.x; xh.y = (_Float16)xv.y;
      v8h hv;
#pragma unroll
      for (int j = 0; j < 8; ++j)
        hv[j] = (_Float16)lrelu(FDOT2(xh, wv[j], bb[j]));
      *(v8h*)(H + r*128 + ((ty ^ (r & 15)) << 3)) = hv;
    }
  }
  __syncthreads();

  fh_layer64(H, g_w16 + OFF_FW,         f2b, w, lm, q);
  fh_layer64(H, g_w16 + OFF_FW + 16384, f3b, w, lm, q);
  fh_layer64(H, g_w16 + OFF_FW + 32768, f4b, w, lm, q);
  fh_layer64(H, g_w16 + OFF_FW + 49152, f5b, w, lm, q);

  // head: 128 threads, thread = (row r, ch c)
  if (t < 128){
    const int r = t >> 1, c = t & 1, rsw = r & 15;
    float s = ffb[c];
    const v8h* wf = (const v8h*)(g_w16 + OFF_FFW + c*128);
#pragma unroll
    for (int ck = 0; ck < 16; ++ck){
      v8h h = *(const v8h*)(H + r*128 + ((ck ^ rsw) << 3));
      s = dot8(h, wf[ck], s);
    }
    const int row = b*64 + r;
    if (row < NPTS) g_fh[row*2 + c] = s;
  }
}

// ================= vnet block body: 4 wave-private waves x 16 rows =================
__device__ __forceinline__ void vfwd_mfma(const _Float16* zin, _Float16* zout,
    const _Float16* __restrict__ Wz, const _Float16* __restrict__ WxT,
    float d0, float d1, int lm, int q)
{
  v4f acc[4];
#pragma unroll
  for (int mt = 0; mt < 4; ++mt) acc[mt] = (v4f){0.f,0.f,0.f,0.f};
  const int rs = lm & 7;
#pragma unroll
  for (int kt = 0; kt < 2; ++kt){
    v8h B = *(const v8h*)(zin + lm*64 + (((kt*4 + q) ^ rs) << 3));
#pragma unroll
    for (int mt = 0; mt < 4; ++mt){
      v8h A = *(const v8h*)(Wz + (mt*16 + lm)*64 + kt*32 + q*8);
      acc[mt] = __builtin_amdgcn_mfma_f32_16x16x32_f16(A, B, acc[mt], 0,0,0);
    }
  }
#pragma unroll
  for (int mt = 0; mt < 4; ++mt){
    const int o0 = mt*16 + q*4;
    v4h hv;
#pragma unroll
    for (int reg = 0; reg < 4; ++reg){
      const int o = o0 + reg;
      const float v = acc[mt][reg] + (float)WxT[o]*d0 + (float)WxT[64 + o]*d1;
      hv[reg] = (_Float16)srelu(v);
    }
    *(v4h*)(zout + lm*64 + (((o0 >> 3) ^ rs) << 3) + (o0 & 7)) = hv;
  }
}

__device__ __forceinline__ void vbwd_mfma(const _Float16* gin, _Float16* zio,
    const _Float16* __restrict__ WT, int lm, int q)
{
  v4f acc[4];
#pragma unroll
  for (int mt = 0; mt < 4; ++mt) acc[mt] = (v4f){0.f,0.f,0.f,0.f};
  const int rs = lm & 7;
#pragma unroll
  for (int kt = 0; kt < 2; ++kt){
    v8h B = *(const v8h*)(gin + lm*64 + (((kt*4 + q) ^ rs) << 3));
#pragma unroll
    for (int mt = 0; mt < 4; ++mt){
      v8h A = *(const v8h*)(WT + (mt*16 + lm)*64 + kt*32 + q*8);
      acc[mt] = __builtin_amdgcn_mfma_f32_16x16x32_f16(A, B, acc[mt], 0,0,0);
    }
  }
#pragma unroll
  for (int mt = 0; mt < 4; ++mt){
    const int k0 = mt*16 + q*4;
    _Float16* p = zio + lm*64 + (((k0 >> 3) ^ rs) << 3) + (k0 & 7);
    v4h zv = *(const v4h*)p;
    v4h gv;
#pragma unroll
    for (int reg = 0; reg < 4; ++reg)
      gv[reg] = (_Float16)(acc[mt][reg] * sreluD_from_z((float)zv[reg]));
    *(v4h*)p = gv;
  }
}

__device__ __forceinline__ void vnet_body(int b, char* smem,
  const float* __restrict__ X, const float* __restrict__ Xst,
  const float* __restrict__ Vfx)
{
  const int t  = threadIdx.x;
  const int w  = t >> 6;
  const int l  = t & 63;
  const int lm = l & 15;
  const int q  = l >> 4;

  _Float16* const Z1 = (_Float16*)(smem + w*6144);        // [16][64] swz8
  _Float16* const Z2 = Z1 + 1024;
  _Float16* const Z3 = Z1 + 2048;

  const int rowi = b*64 + w*16 + lm;
  const int rc = rowi < NPTS ? rowi : NPTS-1;
  const float2 xx = *(const float2*)(X   + rc*2);
  const float2 xs = *(const float2*)(Xst + rc*2);
  const float d0 = xx.x - xs.x, d1 = xx.y - xs.y;
  const float vfx0 = Vfx[0], vfx1 = Vfx[1];
  const int rs = lm & 7;

  // z1 = srelu(Vl1 @ d)
  {
    v8h w0a = *(const v8h*)(g_w16 + OFF_VL1T + q*16);
    v8h w0b = *(const v8h*)(g_w16 + OFF_VL1T + q*16 + 8);
    v8h w1a = *(const v8h*)(g_w16 + OFF_VL1T + 64 + q*16);
    v8h w1b = *(const v8h*)(g_w16 + OFF_VL1T + 64 + q*16 + 8);
    v8h za, zb;
#pragma unroll
    for (int j = 0; j < 8; ++j){
      za[j] = (_Float16)srelu(fmaf(d0, (float)w0a[j], d1 * (float)w1a[j]));
      zb[j] = (_Float16)srelu(fmaf(d0, (float)w0b[j], d1 * (float)w1b[j]));
    }
    *(v8h*)(Z1 + lm*64 + (((q*2    ) ^ rs) << 3)) = za;
    *(v8h*)(Z1 + lm*64 + (((q*2 + 1) ^ rs) << 3)) = zb;
  }

  // z2, z3
  vfwd_mfma(Z1, Z2, g_w16 + OFF_V2Z, g_w16 + OFF_V2XT, d0, d1, lm, q);
  vfwd_mfma(Z2, Z3, g_w16 + OFF_V3Z, g_w16 + OFF_V3XT, d0, d1, lm, q);

  // zf head via MFMA (A row 0 = Vfz)
  float VVr, sf;
  {
    v4f aS = (v4f){0.f,0.f,0.f,0.f};
#pragma unroll
    for (int kt = 0; kt < 2; ++kt){
      v8h A = *(const v8h*)(g_w16 + OFF_VFZ + lm*64 + kt*32 + q*8);
      v8h B = *(const v8h*)(Z3 + lm*64 + (((kt*4 + q) ^ rs) << 3));
      aS = __builtin_amdgcn_mfma_f32_16x16x32_f16(A, B, aS, 0,0,0);
    }
    const float af = fmaf(vfx0, d0, fmaf(vfx1, d1, aS[0]));
    const float zf = srelu(af);
    VVr = srelu(zf) + 0.01f * fmaf(d0, d0, d1*d1);
    sf  = sreluD(zf) * sreluD(af);
  }

  // u3 = Vfz * srelu'(a3) (sf deferred; in place over Z3)
#pragma unroll
  for (int cc = 0; cc < 2; ++cc){
    const int c = q*2 + cc;
    _Float16* p = Z3 + lm*64 + ((c ^ rs) << 3);
    v8h z  = *(const v8h*)p;
    v8h vf = *(const v8h*)(g_w16 + OFF_VFZ + c*8);
    v8h u;
#pragma unroll
    for (int j = 0; j < 8; ++j)
      u[j] = (_Float16)((float)vf[j] * sreluD_from_z((float)z[j]));
    *(v8h*)p = u;
  }

  // backward (in place)
  vbwd_mfma(Z3, Z2, g_w16 + OFF_V3ZT, lm, q);
  vbwd_mfma(Z2, Z1, g_w16 + OFF_V2ZT, lm, q);

  // gradV via MFMA (A rows 0/1 = Wx^T); apply sf once
  float g0, g1;
  {
    v4f aG = (v4f){0.f,0.f,0.f,0.f};
    const _Float16* Zs[3] = {Z1, Z2, Z3};
    const int       Ws[3] = {OFF_VL1T, OFF_V2XT, OFF_V3XT};
#pragma unroll
    for (int li = 0; li < 3; ++li){
#pragma unroll
      for (int kt = 0; kt < 2; ++kt){
        v8h A = *(const v8h*)(g_w16 + Ws[li] + lm*64 + kt*32 + q*8);
        v8h B = *(const v8h*)(Zs[li] + lm*64 + (((kt*4 + q) ^ rs) << 3));
        aG = __builtin_amdgcn_mfma_f32_16x16x32_f16(A, B, aG, 0,0,0);
      }
    }
    g0 = fmaf(0.02f, d0, sf * (vfx0 + aG[0]));
    g1 = fmaf(0.02f, d1, sf * (vfx1 + aG[1]));
  }

  // write (g0, g1, V) for the combine kernel (q==0 lanes)
  if (q == 0 && rowi < NPTS)
    g_grad[rowi] = make_float4(g0, g1, VVr, 0.f);
}

// ================= fused heterogeneous kernel =================
__global__ __launch_bounds__(256, 4) void fused_kernel(
  const float* __restrict__ X, const float* __restrict__ Xst,
  const float* __restrict__ Vfx,
  const float* __restrict__ f1b, const float* __restrict__ f2b,
  const float* __restrict__ f3b, const float* __restrict__ f4b,
  const float* __restrict__ f5b, const float* __restrict__ ffb)
{
  __shared__ __align__(16) char smem[24576];   // max(16 KB fhat, 24 KB vnet)
  const int g = blockIdx.x;
  if ((g & 1) == 0){
    fhat_body(g >> 1, (_Float16*)smem, X, f1b, f2b, f3b, f4b, f5b, ffb);
  } else {
    vnet_body(g >> 1, smem, X, Xst, Vfx);
  }
}

// ================= combine epilogue (memory-bound, ~16 MB) =================
__global__ __launch_bounds__(256) void combine_kernel(float* __restrict__ out)
{
  const int i = blockIdx.x * 256 + threadIdx.x;
  if (i >= NPTS) return;
  const float2 fh = *(const float2*)(g_fh + i*2);
  const float4 gr = g_grad[i];
  const float Vn  = fmaf(gr.x, gr.x, gr.y*gr.y);
  const float num = fmaf(0.1f, gr.z, fmaf(fh.x, gr.x, fh.y*gr.y));
  const float fm  = fmaxf(num, 0.f) / (Vn + 1e-10f);
  float2 o;
  o.x = fmaf(-gr.x, fm, fh.x);
  o.y = fmaf(-gr.y, fm, fh.y);
  *(float2*)(out + i*2) = o;
}

extern "C" void kernel_launch(void* const* d_in, const int* in_sizes, int n_in,
                              void* d_out, int out_size, void* d_ws, size_t ws_size,
                              hipStream_t stream)
{
  (void)d_ws; (void)ws_size; (void)n_in; (void)in_sizes; (void)out_size;
  const float* X   = (const float*)d_in[0];
  const float* Xst = (const float*)d_in[1];
  const float* Vl1 = (const float*)d_in[2];
  const float* V2x = (const float*)d_in[3];
  const float* V2z = (const float*)d_in[4];
  const float* V3x = (const float*)d_in[5];
  const float* V3z = (const float*)d_in[6];
  const float* Vfx = (const float*)d_in[7];
  const float* Vfz = (const float*)d_in[8];
  const float* f1w = (const float*)d_in[9];
  const float* f1b = (const float*)d_in[10];
  const float* f2w = (const float*)d_in[11];
  const float* f2b = (const float*)d_in[12];
  const float* f3w = (const float*)d_in[13];
  const float* f3b = (const float*)d_in[14];
  const float* f4w = (const float*)d_in[15];
  const float* f4b = (const float*)d_in[16];
  const float* f5w = (const float*)d_in[17];
  const float* f5b = (const float*)d_in[18];
  const float* ffw = (const float*)d_in[19];
  const float* ffb = (const float*)d_in[20];

  prep_kernel<<<(W16_TOTAL + 255)/256, 256, 0, stream>>>(
      f2w, f3w, f4w, f5w, V2z, V3z, Vl1, V2x, V3x, Vfz, ffw, f1w);
  fused_kernel<<<FUSED_GRID, 256, 0, stream>>>(
      X, Xst, Vfx, f1b, f2b, f3b, f4b, f5b, ffb);
  combine_kernel<<<(NPTS + 255)/256, 256, 0, stream>>>((float*)d_out);
}

// Round 13
// 381.022 us; speedup vs baseline: 1.0833x; 1.0833x over previous
//
#include <hip/hip_runtime.h>

// ICNN_net_1503238553972 — round 13: heterogeneous fused kernel, fhat@96 rows.
// H = 96x128 f16 = 24576 B == vnet's 24 KB -> fused LDS 24 KB (5-6 blocks/CU)
// while keeping near-R11 per-block amortization (R12's fhat@64 doubled fixed
// costs and regressed). Mix 2:3 via blockIdx%5 (5209 fhat : 7813 vnet).
// launch_bounds(256,4) untouched (tighter bounds spill — R7/R8).
// vnet writes (g0,g1,V) to g_grad; combine kernel (2 rows/thread) finishes.

typedef _Float16 v2h __attribute__((ext_vector_type(2)));
typedef _Float16 v4h __attribute__((ext_vector_type(4)));
typedef _Float16 v8h __attribute__((ext_vector_type(8)));
typedef float    v4f __attribute__((ext_vector_type(4)));

#define NPTS 500000
#define FH_ROWS 96
#define FH_BLK  ((NPTS + FH_ROWS - 1) / FH_ROWS)   // 5209
#define VN_BLK  ((NPTS + 63) / 64)                 // 7813
#define FUSED_GRID (5 * 2605)                      // 13025: 2 fhat + 3 vnet per 5

// offsets in halves inside g_w16
#define OFF_FW    0               // f2..f5: L*16384, [o*128+k]
#define OFF_V2Z   65536           // [j*64+k]
#define OFF_V3Z   69632
#define OFF_V2ZT  73728           // [k*64+j]
#define OFF_V3ZT  77824
#define OFF_VL1T  81920           // [c*64+j]
#define OFF_V2XT  82048
#define OFF_V3XT  82176
#define OFF_VFZ   82304           // [64]
#define OFF_FFW   82368           // [c*128+k]
#define OFF_F1W   82624           // [oc*2+c]
#define W16_DATA  82880
#define W16_TOTAL (W16_DATA + 2048)   // zero pad: junk A-rows stay in-bounds

__device__ __align__(16) _Float16 g_w16[W16_TOTAL];
__device__ __align__(16) float    g_fh[NPTS * 2];   // f_hat per row (fp32)
__device__ __align__(16) float4   g_grad[NPTS];     // (g0, g1, V, pad)

#if defined(__has_builtin)
#if __has_builtin(__builtin_amdgcn_fdot2)
#define FDOT2(a,b,c) __builtin_amdgcn_fdot2((a),(b),(c),false)
#endif
#endif
#ifndef FDOT2
__device__ __forceinline__ float fdot2_fb(v2h a, v2h b, float c){
  return fmaf((float)a.x, (float)b.x, fmaf((float)a.y, (float)b.y, c));
}
#define FDOT2(a,b,c) fdot2_fb((a),(b),(c))
#endif

__device__ __forceinline__ float srelu(float x){
  float c = fminf(fmaxf(x, 0.f), 1.f);
  return c * fmaf(-0.5f, c, x);
}
__device__ __forceinline__ float sreluD(float x){
  return fminf(fmaxf(x, 0.f), 1.f);
}
__device__ __forceinline__ float lrelu(float x){
  return fmaxf(x, 0.01f * x);
}
__device__ __forceinline__ float sreluD_from_z(float z){
  return fminf(sqrtf(2.f * z), 1.f);
}
__device__ __forceinline__ float dot8(v8h a, v8h b, float s){
  const v2h* ap = (const v2h*)&a;
  const v2h* bp = (const v2h*)&b;
  s = FDOT2(ap[0], bp[0], s);
  s = FDOT2(ap[1], bp[1], s);
  s = FDOT2(ap[2], bp[2], s);
  s = FDOT2(ap[3], bp[3], s);
  return s;
}

// ---------------- prep: fp32 weights -> f16 layouts (+zero pad) ----------------
__global__ __launch_bounds__(256) void prep_kernel(
  const float* __restrict__ f2w, const float* __restrict__ f3w,
  const float* __restrict__ f4w, const float* __restrict__ f5w,
  const float* __restrict__ V2z, const float* __restrict__ V3z,
  const float* __restrict__ Vl1, const float* __restrict__ V2x,
  const float* __restrict__ V3x, const float* __restrict__ Vfz,
  const float* __restrict__ ffw, const float* __restrict__ f1w)
{
  const int i = blockIdx.x * 256 + threadIdx.x;
  if (i >= W16_TOTAL) return;
  if (i >= W16_DATA){ g_w16[i] = (_Float16)0.f; return; }
  float v;
  if (i < 65536){
    const float* W[4] = {f2w, f3w, f4w, f5w};
    v = W[i >> 14][i & 16383];
  } else if (i < 69632)  v = V2z[i - 65536];
  else if (i < 73728)    v = V3z[i - 69632];
  else if (i < 77824){ int r = i - 73728; v = V2z[(r & 63)*64 + (r >> 6)]; }
  else if (i < 81920){ int r = i - 77824; v = V3z[(r & 63)*64 + (r >> 6)]; }
  else if (i < 82048){ int r = i - 81920; v = Vl1[(r & 63)*2 + (r >> 6)]; }
  else if (i < 82176){ int r = i - 82048; v = V2x[(r & 63)*2 + (r >> 6)]; }
  else if (i < 82304){ int r = i - 82176; v = V3x[(r & 63)*2 + (r >> 6)]; }
  else if (i < 82368)    v = Vfz[i - 82304];
  else if (i < 82624)    v = ffw[i - 82368];
  else                   v = f1w[i - 82624];
  g_w16[i] = (_Float16)v;
}

// ================= fhat block body: 256 thr, 96 rows (24 KB H) =================
// layer: wave w owns out-ch w*32..w*32+31 for all 96 rows (acc[2][6]).
__device__ __forceinline__ void fh_layer96(_Float16* H,
    const _Float16* __restrict__ Wl, const float* __restrict__ Bp,
    int w, int lm, int q)
{
  v4f acc[2][6];
#pragma unroll
  for (int mt = 0; mt < 2; ++mt)
#pragma unroll
    for (int nt = 0; nt < 6; ++nt) acc[mt][nt] = (v4f){0.f,0.f,0.f,0.f};

#pragma unroll
  for (int kt = 0; kt < 4; ++kt){
    const int sw = ((kt*4 + q) ^ lm) << 3;
    v8h A0 = *(const v8h*)(Wl + (w*32      + lm)*128 + kt*32 + q*8);
    v8h A1 = *(const v8h*)(Wl + (w*32 + 16 + lm)*128 + kt*32 + q*8);
#pragma unroll
    for (int nt = 0; nt < 6; ++nt){
      v8h B = *(const v8h*)(H + (nt*16 + lm)*128 + sw);
      acc[0][nt] = __builtin_amdgcn_mfma_f32_16x16x32_f16(A0, B, acc[0][nt], 0,0,0);
      acc[1][nt] = __builtin_amdgcn_mfma_f32_16x16x32_f16(A1, B, acc[1][nt], 0,0,0);
    }
  }
  __syncthreads();   // all waves' B reads complete before any write
#pragma unroll
  for (int mt = 0; mt < 2; ++mt){
    const int o0 = w*32 + mt*16 + q*4;
    const v4f bv = *(const v4f*)(Bp + o0);
    const int coff = (((o0 >> 3) ^ lm) << 3) + (o0 & 7);
#pragma unroll
    for (int nt = 0; nt < 6; ++nt){
      v4h hv;
      hv[0] = (_Float16)lrelu(acc[mt][nt][0] + bv[0]);
      hv[1] = (_Float16)lrelu(acc[mt][nt][1] + bv[1]);
      hv[2] = (_Float16)lrelu(acc[mt][nt][2] + bv[2]);
      hv[3] = (_Float16)lrelu(acc[mt][nt][3] + bv[3]);
      *(v4h*)(H + (nt*16 + lm)*128 + coff) = hv;
    }
  }
  __syncthreads();   // writes visible before next layer's reads
}

__device__ __forceinline__ void fhat_body(int b, _Float16* H,
  const float* __restrict__ X,
  const float* __restrict__ f1b, const float* __restrict__ f2b,
  const float* __restrict__ f3b, const float* __restrict__ f4b,
  const float* __restrict__ f5b, const float* __restrict__ ffb)
{
  const int t  = threadIdx.x;
  const int w  = t >> 6;
  const int l  = t & 63;
  const int lm = l & 15;
  const int q  = l >> 4;

  // layer1 (K=2, dot2): threads 0..191 = (row r, half hf)
  if (t < 192){
    const int r = t >> 1, hf = t & 1, rsw = r & 15;
    int g = b*FH_ROWS + r; if (g > NPTS-1) g = NPTS-1;
    const float2 xv = *(const float2*)(X + g*2);
    v2h xh; xh.x = (_Float16)xv.x; xh.y = (_Float16)xv.y;
#pragma unroll
    for (int c8 = 0; c8 < 8; ++c8){
      const int c = hf*8 + c8;
      const v4f b0 = *(const v4f*)(f1b + c*8);
      const v4f b1 = *(const v4f*)(f1b + c*8 + 4);
      v8h hv;
#pragma unroll
      for (int j = 0; j < 8; ++j){
        const v2h wv = *(const v2h*)(g_w16 + OFF_F1W + (c*8 + j)*2);
        const float bb = (j < 4) ? b0[j] : b1[j-4];
        hv[j] = (_Float16)lrelu(FDOT2(xh, wv, bb));
      }
      *(v8h*)(H + r*128 + ((c ^ rsw) << 3)) = hv;
    }
  }
  __syncthreads();

  fh_layer96(H, g_w16 + OFF_FW,         f2b, w, lm, q);
  fh_layer96(H, g_w16 + OFF_FW + 16384, f3b, w, lm, q);
  fh_layer96(H, g_w16 + OFF_FW + 32768, f4b, w, lm, q);
  fh_layer96(H, g_w16 + OFF_FW + 49152, f5b, w, lm, q);

  // head: threads 0..191 = (row r, ch c)
  if (t < 192){
    const int r = t >> 1, c = t & 1, rsw = r & 15;
    float s = ffb[c];
    const v8h* wf = (const v8h*)(g_w16 + OFF_FFW + c*128);
#pragma unroll
    for (int ck = 0; ck < 16; ++ck){
      v8h h = *(const v8h*)(H + r*128 + ((ck ^ rsw) << 3));
      s = dot8(h, wf[ck], s);
    }
    const int row = b*FH_ROWS + r;
    if (row < NPTS) g_fh[row*2 + c] = s;
  }
}

// ================= vnet block body: 4 wave-private waves x 16 rows =================
__device__ __forceinline__ void vfwd_mfma(const _Float16* zin, _Float16* zout,
    const _Float16* __restrict__ Wz, const _Float16* __restrict__ WxT,
    float d0, float d1, int lm, int q)
{
  v4f acc[4];
#pragma unroll
  for (int mt = 0; mt < 4; ++mt) acc[mt] = (v4f){0.f,0.f,0.f,0.f};
  const int rs = lm & 7;
#pragma unroll
  for (int kt = 0; kt < 2; ++kt){
    v8h B = *(const v8h*)(zin + lm*64 + (((kt*4 + q) ^ rs) << 3));
#pragma unroll
    for (int mt = 0; mt < 4; ++mt){
      v8h A = *(const v8h*)(Wz + (mt*16 + lm)*64 + kt*32 + q*8);
      acc[mt] = __builtin_amdgcn_mfma_f32_16x16x32_f16(A, B, acc[mt], 0,0,0);
    }
  }
#pragma unroll
  for (int mt = 0; mt < 4; ++mt){
    const int o0 = mt*16 + q*4;
    v4h hv;
#pragma unroll
    for (int reg = 0; reg < 4; ++reg){
      const int o = o0 + reg;
      const float v = acc[mt][reg] + (float)WxT[o]*d0 + (float)WxT[64 + o]*d1;
      hv[reg] = (_Float16)srelu(v);
    }
    *(v4h*)(zout + lm*64 + (((o0 >> 3) ^ rs) << 3) + (o0 & 7)) = hv;
  }
}

__device__ __forceinline__ void vbwd_mfma(const _Float16* gin, _Float16* zio,
    const _Float16* __restrict__ WT, int lm, int q)
{
  v4f acc[4];
#pragma unroll
  for (int mt = 0; mt < 4; ++mt) acc[mt] = (v4f){0.f,0.f,0.f,0.f};
  const int rs = lm & 7;
#pragma unroll
  for (int kt = 0; kt < 2; ++kt){
    v8h B = *(const v8h*)(gin + lm*64 + (((kt*4 + q) ^ rs) << 3));
#pragma unroll
    for (int mt = 0; mt < 4; ++mt){
      v8h A = *(const v8h*)(WT + (mt*16 + lm)*64 + kt*32 + q*8);
      acc[mt] = __builtin_amdgcn_mfma_f32_16x16x32_f16(A, B, acc[mt], 0,0,0);
    }
  }
#pragma unroll
  for (int mt = 0; mt < 4; ++mt){
    const int k0 = mt*16 + q*4;
    _Float16* p = zio + lm*64 + (((k0 >> 3) ^ rs) << 3) + (k0 & 7);
    v4h zv = *(const v4h*)p;
    v4h gv;
#pragma unroll
    for (int reg = 0; reg < 4; ++reg)
      gv[reg] = (_Float16)(acc[mt][reg] * sreluD_from_z((float)zv[reg]));
    *(v4h*)p = gv;
  }
}

__device__ __forceinline__ void vnet_body(int b, char* smem,
  const float* __restrict__ X, const float* __restrict__ Xst,
  const float* __restrict__ Vfx)
{
  const int t  = threadIdx.x;
  const int w  = t >> 6;
  const int l  = t & 63;
  const int lm = l & 15;
  const int q  = l >> 4;

  _Float16* const Z1 = (_Float16*)(smem + w*6144);        // [16][64] swz8
  _Float16* const Z2 = Z1 + 1024;
  _Float16* const Z3 = Z1 + 2048;

  const int rowi = b*64 + w*16 + lm;
  const int rc = rowi < NPTS ? rowi : NPTS-1;
  const float2 xx = *(const float2*)(X   + rc*2);
  const float2 xs = *(const float2*)(Xst + rc*2);
  const float d0 = xx.x - xs.x, d1 = xx.y - xs.y;
  const float vfx0 = Vfx[0], vfx1 = Vfx[1];
  const int rs = lm & 7;

  // z1 = srelu(Vl1 @ d)
  {
    v8h w0a = *(const v8h*)(g_w16 + OFF_VL1T + q*16);
    v8h w0b = *(const v8h*)(g_w16 + OFF_VL1T + q*16 + 8);
    v8h w1a = *(const v8h*)(g_w16 + OFF_VL1T + 64 + q*16);
    v8h w1b = *(const v8h*)(g_w16 + OFF_VL1T + 64 + q*16 + 8);
    v8h za, zb;
#pragma unroll
    for (int j = 0; j < 8; ++j){
      za[j] = (_Float16)srelu(fmaf(d0, (float)w0a[j], d1 * (float)w1a[j]));
      zb[j] = (_Float16)srelu(fmaf(d0, (float)w0b[j], d1 * (float)w1b[j]));
    }
    *(v8h*)(Z1 + lm*64 + (((q*2    ) ^ rs) << 3)) = za;
    *(v8h*)(Z1 + lm*64 + (((q*2 + 1) ^ rs) << 3)) = zb;
  }

  // z2, z3
  vfwd_mfma(Z1, Z2, g_w16 + OFF_V2Z, g_w16 + OFF_V2XT, d0, d1, lm, q);
  vfwd_mfma(Z2, Z3, g_w16 + OFF_V3Z, g_w16 + OFF_V3XT, d0, d1, lm, q);

  // zf head via MFMA (A row 0 = Vfz)
  float VVr, sf;
  {
    v4f aS = (v4f){0.f,0.f,0.f,0.f};
#pragma unroll
    for (int kt = 0; kt < 2; ++kt){
      v8h A = *(const v8h*)(g_w16 + OFF_VFZ + lm*64 + kt*32 + q*8);
      v8h B = *(const v8h*)(Z3 + lm*64 + (((kt*4 + q) ^ rs) << 3));
      aS = __builtin_amdgcn_mfma_f32_16x16x32_f16(A, B, aS, 0,0,0);
    }
    const float af = fmaf(vfx0, d0, fmaf(vfx1, d1, aS[0]));
    const float zf = srelu(af);
    VVr = srelu(zf) + 0.01f * fmaf(d0, d0, d1*d1);
    sf  = sreluD(zf) * sreluD(af);
  }

  // u3 = Vfz * srelu'(a3) (sf deferred; in place over Z3)
#pragma unroll
  for (int cc = 0; cc < 2; ++cc){
    const int c = q*2 + cc;
    _Float16* p = Z3 + lm*64 + ((c ^ rs) << 3);
    v8h z  = *(const v8h*)p;
    v8h vf = *(const v8h*)(g_w16 + OFF_VFZ + c*8);
    v8h u;
#pragma unroll
    for (int j = 0; j < 8; ++j)
      u[j] = (_Float16)((float)vf[j] * sreluD_from_z((float)z[j]));
    *(v8h*)p = u;
  }

  // backward (in place)
  vbwd_mfma(Z3, Z2, g_w16 + OFF_V3ZT, lm, q);
  vbwd_mfma(Z2, Z1, g_w16 + OFF_V2ZT, lm, q);

  // gradV via MFMA (A rows 0/1 = Wx^T); apply sf once
  float g0, g1;
  {
    v4f aG = (v4f){0.f,0.f,0.f,0.f};
    const _Float16* Zs[3] = {Z1, Z2, Z3};
    const int       Ws[3] = {OFF_VL1T, OFF_V2XT, OFF_V3XT};
#pragma unroll
    for (int li = 0; li < 3; ++li){
#pragma unroll
      for (int kt = 0; kt < 2; ++kt){
        v8h A = *(const v8h*)(g_w16 + Ws[li] + lm*64 + kt*32 + q*8);
        v8h B = *(const v8h*)(Zs[li] + lm*64 + (((kt*4 + q) ^ rs) << 3));
        aG = __builtin_amdgcn_mfma_f32_16x16x32_f16(A, B, aG, 0,0,0);
      }
    }
    g0 = fmaf(0.02f, d0, sf * (vfx0 + aG[0]));
    g1 = fmaf(0.02f, d1, sf * (vfx1 + aG[1]));
  }

  // write (g0, g1, V) for the combine kernel (q==0 lanes)
  if (q == 0 && rowi < NPTS)
    g_grad[rowi] = make_float4(g0, g1, VVr, 0.f);
}

// ================= fused heterogeneous kernel =================
__global__ __launch_bounds__(256, 4) void fused_kernel(
  const float* __restrict__ X, const float* __restrict__ Xst,
  const float* __restrict__ Vfx,
  const float* __restrict__ f1b, const float* __restrict__ f2b,
  const float* __restrict__ f3b, const float* __restrict__ f4b,
  const float* __restrict__ f5b, const float* __restrict__ ffb)
{
  __shared__ __align__(16) char smem[24576];   // fhat H 24 KB == vnet 24 KB
  const int g = blockIdx.x;
  const int grp = g / 5, sel = g % 5;
  if (sel < 2){
    const int b = grp*2 + sel;
    if (b < FH_BLK)
      fhat_body(b, (_Float16*)smem, X, f1b, f2b, f3b, f4b, f5b, ffb);
  } else {
    const int b = grp*3 + (sel - 2);
    if (b < VN_BLK)
      vnet_body(b, smem, X, Xst, Vfx);
  }
}

// ================= combine epilogue (2 rows/thread, ~16 MB) =================
__global__ __launch_bounds__(256) void combine_kernel(float* __restrict__ out)
{
  const int idx = blockIdx.x * 256 + threadIdx.x;
  const int i0 = idx * 2;
  if (i0 >= NPTS) return;
  const float4 fh2 = *(const float4*)(g_fh + i0*2);   // rows i0, i0+1
  const float4 ga = g_grad[i0];
  const float4 gb = g_grad[i0 + 1];
  float4 o;
  {
    const float Vn  = fmaf(ga.x, ga.x, ga.y*ga.y);
    const float num = fmaf(0.1f, ga.z, fmaf(fh2.x, ga.x, fh2.y*ga.y));
    const float fm  = fmaxf(num, 0.f) / (Vn + 1e-10f);
    o.x = fmaf(-ga.x, fm, fh2.x);
    o.y = fmaf(-ga.y, fm, fh2.y);
  }
  {
    const float Vn  = fmaf(gb.x, gb.x, gb.y*gb.y);
    const float num = fmaf(0.1f, gb.z, fmaf(fh2.z, gb.x, fh2.w*gb.y));
    const float fm  = fmaxf(num, 0.f) / (Vn + 1e-10f);
    o.z = fmaf(-gb.x, fm, fh2.z);
    o.w = fmaf(-gb.y, fm, fh2.w);
  }
  *(float4*)(out + i0*2) = o;
}

extern "C" void kernel_launch(void* const* d_in, const int* in_sizes, int n_in,
                              void* d_out, int out_size, void* d_ws, size_t ws_size,
                              hipStream_t stream)
{
  (void)d_ws; (void)ws_size; (void)n_in; (void)in_sizes; (void)out_size;
  const float* X   = (const float*)d_in[0];
  const float* Xst = (const float*)d_in[1];
  const float* Vl1 = (const float*)d_in[2];
  const float* V2x = (const float*)d_in[3];
  const float* V2z = (const float*)d_in[4];
  const float* V3x = (const float*)d_in[5];
  const float* V3z = (const float*)d_in[6];
  const float* Vfx = (const float*)d_in[7];
  const float* Vfz = (const float*)d_in[8];
  const float* f1w = (const float*)d_in[9];
  const float* f1b = (const float*)d_in[10];
  const float* f2w = (const float*)d_in[11];
  const float* f2b = (const float*)d_in[12];
  const float* f3w = (const float*)d_in[13];
  const float* f3b = (const float*)d_in[14];
  const float* f4w = (const float*)d_in[15];
  const float* f4b = (const float*)d_in[16];
  const float* f5w = (const float*)d_in[17];
  const float* f5b = (const float*)d_in[18];
  const float* ffw = (const float*)d_in[19];
  const float* ffb = (const float*)d_in[20];

  prep_kernel<<<(W16_TOTAL + 255)/256, 256, 0, stream>>>(
      f2w, f3w, f4w, f5w, V2z, V3z, Vl1, V2x, V3x, Vfz, ffw, f1w);
  fused_kernel<<<FUSED_GRID, 256, 0, stream>>>(
      X, Xst, Vfx, f1b, f2b, f3b, f4b, f5b, ffb);
  combine_kernel<<<(NPTS/2 + 255)/256, 256, 0, stream>>>((float*)d_out);
}

// Round 15
// 364.298 us; speedup vs baseline: 1.1331x; 1.0459x over previous
//
#include <hip/hip_runtime.h>

// ICNN_net_1503238553972 — round 15: R14 (packed f16 activations on the R11
// structure) with the cvt_pkrtz type clash fixed: the builtin returns
// __fp16x2; bit-cast it into our _Float16x2 (same bits) via cvt_pk().
// Structure: fhat@128 + vnet 1:2 mix, 32 KB LDS, launch_bounds(256,4).

typedef _Float16 v2h __attribute__((ext_vector_type(2)));
typedef __fp16   v2hf __attribute__((ext_vector_type(2)));
typedef _Float16 v4h __attribute__((ext_vector_type(4)));
typedef _Float16 v8h __attribute__((ext_vector_type(8)));
typedef float    v4f __attribute__((ext_vector_type(4)));

__device__ __forceinline__ v2h cvt_pk(float a, float b){
  v2hf r = __builtin_amdgcn_cvt_pkrtz(a, b);
  union { v2hf f; v2h h; } u; u.f = r;
  return u.h;
}

#define NPTS 500000
#define FH_BLK  ((NPTS + 127) / 128)   // 3907
#define VN_BLK  ((NPTS + 63) / 64)     // 7813
#define FUSED_GRID 11721               // 3907 fhat + 7813 vnet (+1 spare)

// offsets in halves inside g_w16
#define OFF_FW    0               // f2..f5: L*16384, [o*128+k]
#define OFF_V2Z   65536           // [j*64+k]
#define OFF_V3Z   69632
#define OFF_V2ZT  73728           // [k*64+j]
#define OFF_V3ZT  77824
#define OFF_VL1T  81920           // [c*64+j]
#define OFF_V2XT  82048
#define OFF_V3XT  82176
#define OFF_VFZ   82304           // [64]
#define OFF_FFW   82368           // [c*128+k]
#define OFF_F1W   82624           // [oc*2+c]
#define W16_DATA  82880
#define W16_TOTAL (W16_DATA + 2048)   // zero pad: junk A-rows stay in-bounds

__device__ __align__(16) _Float16 g_w16[W16_TOTAL];
__device__ __align__(16) float    g_fh[NPTS * 2];   // f_hat per row (fp32)
__device__ __align__(16) float4   g_grad[NPTS];     // (g0, g1, V, pad)

#if defined(__has_builtin)
#if __has_builtin(__builtin_amdgcn_fdot2)
#define FDOT2(a,b,c) __builtin_amdgcn_fdot2((a),(b),(c),false)
#endif
#endif
#ifndef FDOT2
__device__ __forceinline__ float fdot2_fb(v2h a, v2h b, float c){
  return fmaf((float)a.x, (float)b.x, fmaf((float)a.y, (float)b.y, c));
}
#define FDOT2(a,b,c) fdot2_fb((a),(b),(c))
#endif

__device__ __forceinline__ float srelu(float x){
  float c = fminf(fmaxf(x, 0.f), 1.f);
  return c * fmaf(-0.5f, c, x);
}
__device__ __forceinline__ float sreluD(float x){
  return fminf(fmaxf(x, 0.f), 1.f);
}
__device__ __forceinline__ float sreluD_from_z(float z){
  return fminf(sqrtf(2.f * z), 1.f);
}
__device__ __forceinline__ float dot8(v8h a, v8h b, float s){
  const v2h* ap = (const v2h*)&a;
  const v2h* bp = (const v2h*)&b;
  s = FDOT2(ap[0], bp[0], s);
  s = FDOT2(ap[1], bp[1], s);
  s = FDOT2(ap[2], bp[2], s);
  s = FDOT2(ap[3], bp[3], s);
  return s;
}

// ---- packed f16 activations (2 f32 in -> 2 f16 out) ----
__device__ __forceinline__ v2h lrelu_pk(float a, float b){
  v2h x = cvt_pk(a, b);
  v2h m = x * (v2h){(_Float16)0.01f, (_Float16)0.01f};
  return __builtin_elementwise_max(x, m);
}
__device__ __forceinline__ v2h srelu_pk(float a, float b){
  v2h x = cvt_pk(a, b);
  const v2h z0 = (v2h){(_Float16)0.f, (_Float16)0.f};
  const v2h o1 = (v2h){(_Float16)1.f, (_Float16)1.f};
  const v2h hf = (v2h){(_Float16)0.5f, (_Float16)0.5f};
  v2h c = __builtin_elementwise_min(__builtin_elementwise_max(x, z0), o1);
  v2h t = x - c * hf;
  return c * t;
}

// ---------------- prep: fp32 weights -> f16 layouts (+zero pad) ----------------
__global__ __launch_bounds__(256) void prep_kernel(
  const float* __restrict__ f2w, const float* __restrict__ f3w,
  const float* __restrict__ f4w, const float* __restrict__ f5w,
  const float* __restrict__ V2z, const float* __restrict__ V3z,
  const float* __restrict__ Vl1, const float* __restrict__ V2x,
  const float* __restrict__ V3x, const float* __restrict__ Vfz,
  const float* __restrict__ ffw, const float* __restrict__ f1w)
{
  const int i = blockIdx.x * 256 + threadIdx.x;
  if (i >= W16_TOTAL) return;
  if (i >= W16_DATA){ g_w16[i] = (_Float16)0.f; return; }
  float v;
  if (i < 65536){
    const float* W[4] = {f2w, f3w, f4w, f5w};
    v = W[i >> 14][i & 16383];
  } else if (i < 69632)  v = V2z[i - 65536];
  else if (i < 73728)    v = V3z[i - 69632];
  else if (i < 77824){ int r = i - 73728; v = V2z[(r & 63)*64 + (r >> 6)]; }
  else if (i < 81920){ int r = i - 77824; v = V3z[(r & 63)*64 + (r >> 6)]; }
  else if (i < 82048){ int r = i - 81920; v = Vl1[(r & 63)*2 + (r >> 6)]; }
  else if (i < 82176){ int r = i - 82048; v = V2x[(r & 63)*2 + (r >> 6)]; }
  else if (i < 82304){ int r = i - 82176; v = V3x[(r & 63)*2 + (r >> 6)]; }
  else if (i < 82368)    v = Vfz[i - 82304];
  else if (i < 82624)    v = ffw[i - 82368];
  else                   v = f1w[i - 82624];
  g_w16[i] = (_Float16)v;
}

// ================= fhat block body: 256 thr, 128 rows =================
__device__ __forceinline__ void fh_layer(_Float16* H,
    const _Float16* __restrict__ Wl, const float* __restrict__ Bp,
    int w, int lm, int q)
{
  v4f acc[2][8];
#pragma unroll
  for (int mt = 0; mt < 2; ++mt)
#pragma unroll
    for (int nt = 0; nt < 8; ++nt) acc[mt][nt] = (v4f){0.f,0.f,0.f,0.f};

#pragma unroll
  for (int kt = 0; kt < 4; ++kt){
    const int sw = ((kt*4 + q) ^ lm) << 3;
    v8h A0 = *(const v8h*)(Wl + (w*32      + lm)*128 + kt*32 + q*8);
    v8h A1 = *(const v8h*)(Wl + (w*32 + 16 + lm)*128 + kt*32 + q*8);
#pragma unroll
    for (int nt = 0; nt < 8; ++nt){
      v8h B = *(const v8h*)(H + (nt*16 + lm)*128 + sw);
      acc[0][nt] = __builtin_amdgcn_mfma_f32_16x16x32_f16(A0, B, acc[0][nt], 0,0,0);
      acc[1][nt] = __builtin_amdgcn_mfma_f32_16x16x32_f16(A1, B, acc[1][nt], 0,0,0);
    }
  }
  __syncthreads();   // all waves' B reads complete before any write
#pragma unroll
  for (int mt = 0; mt < 2; ++mt){
    const int o0 = w*32 + mt*16 + q*4;
    const v4f bv = *(const v4f*)(Bp + o0);
    const int coff = (((o0 >> 3) ^ lm) << 3) + (o0 & 7);
#pragma unroll
    for (int nt = 0; nt < 8; ++nt){
      v4h hv;
      *(v2h*)&hv       = lrelu_pk(acc[mt][nt][0] + bv[0], acc[mt][nt][1] + bv[1]);
      *((v2h*)&hv + 1) = lrelu_pk(acc[mt][nt][2] + bv[2], acc[mt][nt][3] + bv[3]);
      *(v4h*)(H + (nt*16 + lm)*128 + coff) = hv;
    }
  }
  __syncthreads();   // writes visible before next layer's reads
}

__device__ __forceinline__ void fhat_body(int b, _Float16* H,
  const float* __restrict__ X,
  const float* __restrict__ f1b, const float* __restrict__ f2b,
  const float* __restrict__ f3b, const float* __restrict__ f4b,
  const float* __restrict__ f5b, const float* __restrict__ ffb)
{
  const int t  = threadIdx.x;
  const int w  = t >> 6;
  const int l  = t & 63;
  const int lm = l & 15;
  const int q  = l >> 4;

  // layer1 (K=2, dot2): thread = (row r, half hf)
  {
    const int r = t >> 1, hf = t & 1, rsw = r & 15;
    int g = b*128 + r; if (g > NPTS-1) g = NPTS-1;
    const float2 xv = *(const float2*)(X + g*2);
    v2h xh; xh.x = (_Float16)xv.x; xh.y = (_Float16)xv.y;
#pragma unroll
    for (int c8 = 0; c8 < 8; ++c8){
      const int c = hf*8 + c8;
      const v4f b0 = *(const v4f*)(f1b + c*8);
      const v4f b1 = *(const v4f*)(f1b + c*8 + 4);
      float vv[8];
#pragma unroll
      for (int j = 0; j < 8; ++j){
        const v2h wv = *(const v2h*)(g_w16 + OFF_F1W + (c*8 + j)*2);
        const float bb = (j < 4) ? b0[j] : b1[j-4];
        vv[j] = FDOT2(xh, wv, bb);
      }
      v8h hv;
#pragma unroll
      for (int j2 = 0; j2 < 4; ++j2)
        ((v2h*)&hv)[j2] = lrelu_pk(vv[2*j2], vv[2*j2+1]);
      *(v8h*)(H + r*128 + ((c ^ rsw) << 3)) = hv;
    }
  }
  __syncthreads();

  fh_layer(H, g_w16 + OFF_FW,         f2b, w, lm, q);
  fh_layer(H, g_w16 + OFF_FW + 16384, f3b, w, lm, q);
  fh_layer(H, g_w16 + OFF_FW + 32768, f4b, w, lm, q);
  fh_layer(H, g_w16 + OFF_FW + 49152, f5b, w, lm, q);

  // head: thread = (row r, ch c)
  {
    const int r = t >> 1, c = t & 1, rsw = r & 15;
    float s = ffb[c];
    const v8h* wf = (const v8h*)(g_w16 + OFF_FFW + c*128);
#pragma unroll
    for (int ck = 0; ck < 16; ++ck){
      v8h h = *(const v8h*)(H + r*128 + ((ck ^ rsw) << 3));
      s = dot8(h, wf[ck], s);
    }
    const int row = b*128 + r;
    if (row < NPTS) g_fh[row*2 + c] = s;
  }
}

// ================= vnet block body: 4 wave-private waves x 16 rows =================
__device__ __forceinline__ void vfwd_mfma(const _Float16* zin, _Float16* zout,
    const _Float16* __restrict__ Wz, const _Float16* __restrict__ WxT,
    float d0, float d1, int lm, int q)
{
  v4f acc[4];
#pragma unroll
  for (int mt = 0; mt < 4; ++mt) acc[mt] = (v4f){0.f,0.f,0.f,0.f};
  const int rs = lm & 7;
#pragma unroll
  for (int kt = 0; kt < 2; ++kt){
    v8h B = *(const v8h*)(zin + lm*64 + (((kt*4 + q) ^ rs) << 3));
#pragma unroll
    for (int mt = 0; mt < 4; ++mt){
      v8h A = *(const v8h*)(Wz + (mt*16 + lm)*64 + kt*32 + q*8);
      acc[mt] = __builtin_amdgcn_mfma_f32_16x16x32_f16(A, B, acc[mt], 0,0,0);
    }
  }
#pragma unroll
  for (int mt = 0; mt < 4; ++mt){
    const int o0 = mt*16 + q*4;
    float vv[4];
#pragma unroll
    for (int reg = 0; reg < 4; ++reg){
      const int o = o0 + reg;
      vv[reg] = acc[mt][reg] + (float)WxT[o]*d0 + (float)WxT[64 + o]*d1;
    }
    v4h hv;
    *(v2h*)&hv       = srelu_pk(vv[0], vv[1]);
    *((v2h*)&hv + 1) = srelu_pk(vv[2], vv[3]);
    *(v4h*)(zout + lm*64 + (((o0 >> 3) ^ rs) << 3) + (o0 & 7)) = hv;
  }
}

__device__ __forceinline__ void vbwd_mfma(const _Float16* gin, _Float16* zio,
    const _Float16* __restrict__ WT, int lm, int q)
{
  v4f acc[4];
#pragma unroll
  for (int mt = 0; mt < 4; ++mt) acc[mt] = (v4f){0.f,0.f,0.f,0.f};
  const int rs = lm & 7;
#pragma unroll
  for (int kt = 0; kt < 2; ++kt){
    v8h B = *(const v8h*)(gin + lm*64 + (((kt*4 + q) ^ rs) << 3));
#pragma unroll
    for (int mt = 0; mt < 4; ++mt){
      v8h A = *(const v8h*)(WT + (mt*16 + lm)*64 + kt*32 + q*8);
      acc[mt] = __builtin_amdgcn_mfma_f32_16x16x32_f16(A, B, acc[mt], 0,0,0);
    }
  }
#pragma unroll
  for (int mt = 0; mt < 4; ++mt){
    const int k0 = mt*16 + q*4;
    _Float16* p = zio + lm*64 + (((k0 >> 3) ^ rs) << 3) + (k0 & 7);
    v4h zv = *(const v4h*)p;
    float s0 = acc[mt][0] * sreluD_from_z((float)zv[0]);
    float s1 = acc[mt][1] * sreluD_from_z((float)zv[1]);
    float s2 = acc[mt][2] * sreluD_from_z((float)zv[2]);
    float s3 = acc[mt][3] * sreluD_from_z((float)zv[3]);
    v4h gv;
    *(v2h*)&gv       = cvt_pk(s0, s1);
    *((v2h*)&gv + 1) = cvt_pk(s2, s3);
    *(v4h*)p = gv;
  }
}

__device__ __forceinline__ void vnet_body(int b, char* smem,
  const float* __restrict__ X, const float* __restrict__ Xst,
  const float* __restrict__ Vfx)
{
  const int t  = threadIdx.x;
  const int w  = t >> 6;
  const int l  = t & 63;
  const int lm = l & 15;
  const int q  = l >> 4;

  _Float16* const Z1 = (_Float16*)(smem + w*6144);        // [16][64] swz8
  _Float16* const Z2 = Z1 + 1024;
  _Float16* const Z3 = Z1 + 2048;

  const int rowi = b*64 + w*16 + lm;
  const int rc = rowi < NPTS ? rowi : NPTS-1;
  const float2 xx = *(const float2*)(X   + rc*2);
  const float2 xs = *(const float2*)(Xst + rc*2);
  const float d0 = xx.x - xs.x, d1 = xx.y - xs.y;
  const float vfx0 = Vfx[0], vfx1 = Vfx[1];
  const int rs = lm & 7;

  // z1 = srelu(Vl1 @ d)  (packed pairs)
  {
    v8h w0a = *(const v8h*)(g_w16 + OFF_VL1T + q*16);
    v8h w0b = *(const v8h*)(g_w16 + OFF_VL1T + q*16 + 8);
    v8h w1a = *(const v8h*)(g_w16 + OFF_VL1T + 64 + q*16);
    v8h w1b = *(const v8h*)(g_w16 + OFF_VL1T + 64 + q*16 + 8);
    v8h za, zb;
#pragma unroll
    for (int j2 = 0; j2 < 4; ++j2){
      float a0 = fmaf(d0, (float)w0a[2*j2  ], d1 * (float)w1a[2*j2  ]);
      float a1 = fmaf(d0, (float)w0a[2*j2+1], d1 * (float)w1a[2*j2+1]);
      float b0 = fmaf(d0, (float)w0b[2*j2  ], d1 * (float)w1b[2*j2  ]);
      float b1 = fmaf(d0, (float)w0b[2*j2+1], d1 * (float)w1b[2*j2+1]);
      ((v2h*)&za)[j2] = srelu_pk(a0, a1);
      ((v2h*)&zb)[j2] = srelu_pk(b0, b1);
    }
    *(v8h*)(Z1 + lm*64 + (((q*2    ) ^ rs) << 3)) = za;
    *(v8h*)(Z1 + lm*64 + (((q*2 + 1) ^ rs) << 3)) = zb;
  }

  // z2, z3
  vfwd_mfma(Z1, Z2, g_w16 + OFF_V2Z, g_w16 + OFF_V2XT, d0, d1, lm, q);
  vfwd_mfma(Z2, Z3, g_w16 + OFF_V3Z, g_w16 + OFF_V3XT, d0, d1, lm, q);

  // zf head via MFMA (A row 0 = Vfz)
  float VVr, sf;
  {
    v4f aS = (v4f){0.f,0.f,0.f,0.f};
#pragma unroll
    for (int kt = 0; kt < 2; ++kt){
      v8h A = *(const v8h*)(g_w16 + OFF_VFZ + lm*64 + kt*32 + q*8);
      v8h B = *(const v8h*)(Z3 + lm*64 + (((kt*4 + q) ^ rs) << 3));
      aS = __builtin_amdgcn_mfma_f32_16x16x32_f16(A, B, aS, 0,0,0);
    }
    const float af = fmaf(vfx0, d0, fmaf(vfx1, d1, aS[0]));
    const float zf = srelu(af);
    VVr = srelu(zf) + 0.01f * fmaf(d0, d0, d1*d1);
    sf  = sreluD(zf) * sreluD(af);
  }

  // u3 = Vfz * srelu'(a3) (sf deferred; in place over Z3)
#pragma unroll
  for (int cc = 0; cc < 2; ++cc){
    const int c = q*2 + cc;
    _Float16* p = Z3 + lm*64 + ((c ^ rs) << 3);
    v8h z  = *(const v8h*)p;
    v8h vf = *(const v8h*)(g_w16 + OFF_VFZ + c*8);
    float u[8];
#pragma unroll
    for (int j = 0; j < 8; ++j)
      u[j] = (float)vf[j] * sreluD_from_z((float)z[j]);
    v8h uo;
#pragma unroll
    for (int j2 = 0; j2 < 4; ++j2)
      ((v2h*)&uo)[j2] = cvt_pk(u[2*j2], u[2*j2+1]);
    *(v8h*)p = uo;
  }

  // backward (in place)
  vbwd_mfma(Z3, Z2, g_w16 + OFF_V3ZT, lm, q);
  vbwd_mfma(Z2, Z1, g_w16 + OFF_V2ZT, lm, q);

  // gradV via MFMA (A rows 0/1 = Wx^T); apply sf once
  float g0, g1;
  {
    v4f aG = (v4f){0.f,0.f,0.f,0.f};
    const _Float16* Zs[3] = {Z1, Z2, Z3};
    const int       Ws[3] = {OFF_VL1T, OFF_V2XT, OFF_V3XT};
#pragma unroll
    for (int li = 0; li < 3; ++li){
#pragma unroll
      for (int kt = 0; kt < 2; ++kt){
        v8h A = *(const v8h*)(g_w16 + Ws[li] + lm*64 + kt*32 + q*8);
        v8h B = *(const v8h*)(Zs[li] + lm*64 + (((kt*4 + q) ^ rs) << 3));
        aG = __builtin_amdgcn_mfma_f32_16x16x32_f16(A, B, aG, 0,0,0);
      }
    }
    g0 = fmaf(0.02f, d0, sf * (vfx0 + aG[0]));
    g1 = fmaf(0.02f, d1, sf * (vfx1 + aG[1]));
  }

  // write (g0, g1, V) for the combine kernel (q==0 lanes)
  if (q == 0 && rowi < NPTS)
    g_grad[rowi] = make_float4(g0, g1, VVr, 0.f);
}

// ================= fused heterogeneous kernel =================
__global__ __launch_bounds__(256, 4) void fused_kernel(
  const float* __restrict__ X, const float* __restrict__ Xst,
  const float* __restrict__ Vfx,
  const float* __restrict__ f1b, const float* __restrict__ f2b,
  const float* __restrict__ f3b, const float* __restrict__ f4b,
  const float* __restrict__ f5b, const float* __restrict__ ffb)
{
  __shared__ __align__(16) char smem[32768];
  const int g = blockIdx.x;
  const int sel = g % 3;
  if (sel == 0){
    fhat_body(g/3, (_Float16*)smem, X, f1b, f2b, f3b, f4b, f5b, ffb);
  } else {
    const int b = (g/3)*2 + sel - 1;
    if (b < VN_BLK) vnet_body(b, smem, X, Xst, Vfx);
  }
}

// ================= combine epilogue (2 rows/thread, ~16 MB) =================
__global__ __launch_bounds__(256) void combine_kernel(float* __restrict__ out)
{
  const int idx = blockIdx.x * 256 + threadIdx.x;
  const int i0 = idx * 2;
  if (i0 >= NPTS) return;
  const float4 fh2 = *(const float4*)(g_fh + i0*2);   // rows i0, i0+1
  const float4 ga = g_grad[i0];
  const float4 gb = g_grad[i0 + 1];
  float4 o;
  {
    const float Vn  = fmaf(ga.x, ga.x, ga.y*ga.y);
    const float num = fmaf(0.1f, ga.z, fmaf(fh2.x, ga.x, fh2.y*ga.y));
    const float fm  = fmaxf(num, 0.f) / (Vn + 1e-10f);
    o.x = fmaf(-ga.x, fm, fh2.x);
    o.y = fmaf(-ga.y, fm, fh2.y);
  }
  {
    const float Vn  = fmaf(gb.x, gb.x, gb.y*gb.y);
    const float num = fmaf(0.1f, gb.z, fmaf(fh2.z, gb.x, fh2.w*gb.y));
    const float fm  = fmaxf(num, 0.f) / (Vn + 1e-10f);
    o.z = fmaf(-gb.x, fm, fh2.z);
    o.w = fmaf(-gb.y, fm, fh2.w);
  }
  *(float4*)(out + i0*2) = o;
}

extern "C" void kernel_launch(void* const* d_in, const int* in_sizes, int n_in,
                              void* d_out, int out_size, void* d_ws, size_t ws_size,
                              hipStream_t stream)
{
  (void)d_ws; (void)ws_size; (void)n_in; (void)in_sizes; (void)out_size;
  const float* X   = (const float*)d_in[0];
  const float* Xst = (const float*)d_in[1];
  const float* Vl1 = (const float*)d_in[2];
  const float* V2x = (const float*)d_in[3];
  const float* V2z = (const float*)d_in[4];
  const float* V3x = (const float*)d_in[5];
  const float* V3z = (const float*)d_in[6];
  const float* Vfx = (const float*)d_in[7];
  const float* Vfz = (const float*)d_in[8];
  const float* f1w = (const float*)d_in[9];
  const float* f1b = (const float*)d_in[10];
  const float* f2w = (const float*)d_in[11];
  const float* f2b = (const float*)d_in[12];
  const float* f3w = (const float*)d_in[13];
  const float* f3b = (const float*)d_in[14];
  const float* f4w = (const float*)d_in[15];
  const float* f4b = (const float*)d_in[16];
  const float* f5w = (const float*)d_in[17];
  const float* f5b = (const float*)d_in[18];
  const float* ffw = (const float*)d_in[19];
  const float* ffb = (const float*)d_in[20];

  prep_kernel<<<(W16_TOTAL + 255)/256, 256, 0, stream>>>(
      f2w, f3w, f4w, f5w, V2z, V3z, Vl1, V2x, V3x, Vfz, ffw, f1w);
  fused_kernel<<<FUSED_GRID, 256, 0, stream>>>(
      X, Xst, Vfx, f1b, f2b, f3b, f4b, f5b, ffb);
  combine_kernel<<<(NPTS/2 + 255)/256, 256, 0, stream>>>((float*)d_out);
}

// Round 16
// 354.646 us; speedup vs baseline: 1.1639x; 1.0272x over previous
//
#include <hip/hip_runtime.h>

// ICNN_net_1503238553972 — round 16: vnet with 2 independent row-group
// pipelines per wave (ILP attack on the serial ds_read->MFMA->ds_write
// chain). A-fragments (weights) shared between pipelines — loaded once.
// vnet block = 128 rows (4 waves x 2x16); fused grid 1:1 with fhat@128.
// Fused LDS = 48 KB (3 blocks/CU): trading TLP (43%->~37%) for 2x ILP.
// fhat body = R15 (packed f16 activations). launch_bounds(256,4).

typedef _Float16 v2h __attribute__((ext_vector_type(2)));
typedef __fp16   v2hf __attribute__((ext_vector_type(2)));
typedef _Float16 v4h __attribute__((ext_vector_type(4)));
typedef _Float16 v8h __attribute__((ext_vector_type(8)));
typedef float    v4f __attribute__((ext_vector_type(4)));

__device__ __forceinline__ v2h cvt_pk(float a, float b){
  v2hf r = __builtin_amdgcn_cvt_pkrtz(a, b);
  union { v2hf f; v2h h; } u; u.f = r;
  return u.h;
}

#define NPTS 500000
#define FH_BLK  ((NPTS + 127) / 128)   // 3907
#define VN_BLK  ((NPTS + 127) / 128)   // 3907 (128 rows/block now)
#define FUSED_GRID (FH_BLK + VN_BLK)   // 7814

// offsets in halves inside g_w16
#define OFF_FW    0               // f2..f5: L*16384, [o*128+k]
#define OFF_V2Z   65536           // [j*64+k]
#define OFF_V3Z   69632
#define OFF_V2ZT  73728           // [k*64+j]
#define OFF_V3ZT  77824
#define OFF_VL1T  81920           // [c*64+j]
#define OFF_V2XT  82048
#define OFF_V3XT  82176
#define OFF_VFZ   82304           // [64]
#define OFF_FFW   82368           // [c*128+k]
#define OFF_F1W   82624           // [oc*2+c]
#define W16_DATA  82880
#define W16_TOTAL (W16_DATA + 2048)   // zero pad: junk A-rows stay in-bounds

__device__ __align__(16) _Float16 g_w16[W16_TOTAL];
__device__ __align__(16) float    g_fh[NPTS * 2];   // f_hat per row (fp32)
__device__ __align__(16) float4   g_grad[NPTS];     // (g0, g1, V, pad)

#if defined(__has_builtin)
#if __has_builtin(__builtin_amdgcn_fdot2)
#define FDOT2(a,b,c) __builtin_amdgcn_fdot2((a),(b),(c),false)
#endif
#endif
#ifndef FDOT2
__device__ __forceinline__ float fdot2_fb(v2h a, v2h b, float c){
  return fmaf((float)a.x, (float)b.x, fmaf((float)a.y, (float)b.y, c));
}
#define FDOT2(a,b,c) fdot2_fb((a),(b),(c))
#endif

__device__ __forceinline__ float srelu(float x){
  float c = fminf(fmaxf(x, 0.f), 1.f);
  return c * fmaf(-0.5f, c, x);
}
__device__ __forceinline__ float sreluD(float x){
  return fminf(fmaxf(x, 0.f), 1.f);
}
__device__ __forceinline__ float sreluD_from_z(float z){
  return fminf(sqrtf(2.f * z), 1.f);
}
__device__ __forceinline__ float dot8(v8h a, v8h b, float s){
  const v2h* ap = (const v2h*)&a;
  const v2h* bp = (const v2h*)&b;
  s = FDOT2(ap[0], bp[0], s);
  s = FDOT2(ap[1], bp[1], s);
  s = FDOT2(ap[2], bp[2], s);
  s = FDOT2(ap[3], bp[3], s);
  return s;
}

// ---- packed f16 activations (2 f32 in -> 2 f16 out) ----
__device__ __forceinline__ v2h lrelu_pk(float a, float b){
  v2h x = cvt_pk(a, b);
  v2h m = x * (v2h){(_Float16)0.01f, (_Float16)0.01f};
  return __builtin_elementwise_max(x, m);
}
__device__ __forceinline__ v2h srelu_pk(float a, float b){
  v2h x = cvt_pk(a, b);
  const v2h z0 = (v2h){(_Float16)0.f, (_Float16)0.f};
  const v2h o1 = (v2h){(_Float16)1.f, (_Float16)1.f};
  const v2h hf = (v2h){(_Float16)0.5f, (_Float16)0.5f};
  v2h c = __builtin_elementwise_min(__builtin_elementwise_max(x, z0), o1);
  v2h t = x - c * hf;
  return c * t;
}

// ---------------- prep: fp32 weights -> f16 layouts (+zero pad) ----------------
__global__ __launch_bounds__(256) void prep_kernel(
  const float* __restrict__ f2w, const float* __restrict__ f3w,
  const float* __restrict__ f4w, const float* __restrict__ f5w,
  const float* __restrict__ V2z, const float* __restrict__ V3z,
  const float* __restrict__ Vl1, const float* __restrict__ V2x,
  const float* __restrict__ V3x, const float* __restrict__ Vfz,
  const float* __restrict__ ffw, const float* __restrict__ f1w)
{
  const int i = blockIdx.x * 256 + threadIdx.x;
  if (i >= W16_TOTAL) return;
  if (i >= W16_DATA){ g_w16[i] = (_Float16)0.f; return; }
  float v;
  if (i < 65536){
    const float* W[4] = {f2w, f3w, f4w, f5w};
    v = W[i >> 14][i & 16383];
  } else if (i < 69632)  v = V2z[i - 65536];
  else if (i < 73728)    v = V3z[i - 69632];
  else if (i < 77824){ int r = i - 73728; v = V2z[(r & 63)*64 + (r >> 6)]; }
  else if (i < 81920){ int r = i - 77824; v = V3z[(r & 63)*64 + (r >> 6)]; }
  else if (i < 82048){ int r = i - 81920; v = Vl1[(r & 63)*2 + (r >> 6)]; }
  else if (i < 82176){ int r = i - 82048; v = V2x[(r & 63)*2 + (r >> 6)]; }
  else if (i < 82304){ int r = i - 82176; v = V3x[(r & 63)*2 + (r >> 6)]; }
  else if (i < 82368)    v = Vfz[i - 82304];
  else if (i < 82624)    v = ffw[i - 82368];
  else                   v = f1w[i - 82624];
  g_w16[i] = (_Float16)v;
}

// ================= fhat block body: 256 thr, 128 rows =================
__device__ __forceinline__ void fh_layer(_Float16* H,
    const _Float16* __restrict__ Wl, const float* __restrict__ Bp,
    int w, int lm, int q)
{
  v4f acc[2][8];
#pragma unroll
  for (int mt = 0; mt < 2; ++mt)
#pragma unroll
    for (int nt = 0; nt < 8; ++nt) acc[mt][nt] = (v4f){0.f,0.f,0.f,0.f};

#pragma unroll
  for (int kt = 0; kt < 4; ++kt){
    const int sw = ((kt*4 + q) ^ lm) << 3;
    v8h A0 = *(const v8h*)(Wl + (w*32      + lm)*128 + kt*32 + q*8);
    v8h A1 = *(const v8h*)(Wl + (w*32 + 16 + lm)*128 + kt*32 + q*8);
#pragma unroll
    for (int nt = 0; nt < 8; ++nt){
      v8h B = *(const v8h*)(H + (nt*16 + lm)*128 + sw);
      acc[0][nt] = __builtin_amdgcn_mfma_f32_16x16x32_f16(A0, B, acc[0][nt], 0,0,0);
      acc[1][nt] = __builtin_amdgcn_mfma_f32_16x16x32_f16(A1, B, acc[1][nt], 0,0,0);
    }
  }
  __syncthreads();   // all waves' B reads complete before any write
#pragma unroll
  for (int mt = 0; mt < 2; ++mt){
    const int o0 = w*32 + mt*16 + q*4;
    const v4f bv = *(const v4f*)(Bp + o0);
    const int coff = (((o0 >> 3) ^ lm) << 3) + (o0 & 7);
#pragma unroll
    for (int nt = 0; nt < 8; ++nt){
      v4h hv;
      *(v2h*)&hv       = lrelu_pk(acc[mt][nt][0] + bv[0], acc[mt][nt][1] + bv[1]);
      *((v2h*)&hv + 1) = lrelu_pk(acc[mt][nt][2] + bv[2], acc[mt][nt][3] + bv[3]);
      *(v4h*)(H + (nt*16 + lm)*128 + coff) = hv;
    }
  }
  __syncthreads();   // writes visible before next layer's reads
}

__device__ __forceinline__ void fhat_body(int b, _Float16* H,
  const float* __restrict__ X,
  const float* __restrict__ f1b, const float* __restrict__ f2b,
  const float* __restrict__ f3b, const float* __restrict__ f4b,
  const float* __restrict__ f5b, const float* __restrict__ ffb)
{
  const int t  = threadIdx.x;
  const int w  = t >> 6;
  const int l  = t & 63;
  const int lm = l & 15;
  const int q  = l >> 4;

  // layer1 (K=2, dot2): thread = (row r, half hf)
  {
    const int r = t >> 1, hf = t & 1, rsw = r & 15;
    int g = b*128 + r; if (g > NPTS-1) g = NPTS-1;
    const float2 xv = *(const float2*)(X + g*2);
    v2h xh; xh.x = (_Float16)xv.x; xh.y = (_Float16)xv.y;
#pragma unroll
    for (int c8 = 0; c8 < 8; ++c8){
      const int c = hf*8 + c8;
      const v4f b0 = *(const v4f*)(f1b + c*8);
      const v4f b1 = *(const v4f*)(f1b + c*8 + 4);
      float vv[8];
#pragma unroll
      for (int j = 0; j < 8; ++j){
        const v2h wv = *(const v2h*)(g_w16 + OFF_F1W + (c*8 + j)*2);
        const float bb = (j < 4) ? b0[j] : b1[j-4];
        vv[j] = FDOT2(xh, wv, bb);
      }
      v8h hv;
#pragma unroll
      for (int j2 = 0; j2 < 4; ++j2)
        ((v2h*)&hv)[j2] = lrelu_pk(vv[2*j2], vv[2*j2+1]);
      *(v8h*)(H + r*128 + ((c ^ rsw) << 3)) = hv;
    }
  }
  __syncthreads();

  fh_layer(H, g_w16 + OFF_FW,         f2b, w, lm, q);
  fh_layer(H, g_w16 + OFF_FW + 16384, f3b, w, lm, q);
  fh_layer(H, g_w16 + OFF_FW + 32768, f4b, w, lm, q);
  fh_layer(H, g_w16 + OFF_FW + 49152, f5b, w, lm, q);

  // head: thread = (row r, ch c)
  {
    const int r = t >> 1, c = t & 1, rsw = r & 15;
    float s = ffb[c];
    const v8h* wf = (const v8h*)(g_w16 + OFF_FFW + c*128);
#pragma unroll
    for (int ck = 0; ck < 16; ++ck){
      v8h h = *(const v8h*)(H + r*128 + ((ck ^ rsw) << 3));
      s = dot8(h, wf[ck], s);
    }
    const int row = b*128 + r;
    if (row < NPTS) g_fh[row*2 + c] = s;
  }
}

// ================= vnet: 2-pipeline wave-private bodies =================
// fwd: two (zin,zout) pairs share the A-fragments.
__device__ __forceinline__ void vfwd2(const _Float16* zinA, _Float16* zoutA,
    const _Float16* zinB, _Float16* zoutB,
    const _Float16* __restrict__ Wz, const _Float16* __restrict__ WxT,
    float dA0, float dA1, float dB0, float dB1, int lm, int q)
{
  v4f accA[4], accB[4];
#pragma unroll
  for (int mt = 0; mt < 4; ++mt){
    accA[mt] = (v4f){0.f,0.f,0.f,0.f};
    accB[mt] = (v4f){0.f,0.f,0.f,0.f};
  }
  const int rs = lm & 7;
#pragma unroll
  for (int kt = 0; kt < 2; ++kt){
    const int sw = (((kt*4 + q) ^ rs) << 3);
    v8h BA = *(const v8h*)(zinA + lm*64 + sw);
    v8h BB = *(const v8h*)(zinB + lm*64 + sw);
#pragma unroll
    for (int mt = 0; mt < 4; ++mt){
      v8h A = *(const v8h*)(Wz + (mt*16 + lm)*64 + kt*32 + q*8);
      accA[mt] = __builtin_amdgcn_mfma_f32_16x16x32_f16(A, BA, accA[mt], 0,0,0);
      accB[mt] = __builtin_amdgcn_mfma_f32_16x16x32_f16(A, BB, accB[mt], 0,0,0);
    }
  }
#pragma unroll
  for (int mt = 0; mt < 4; ++mt){
    const int o0 = mt*16 + q*4;
    const int off = (((o0 >> 3) ^ rs) << 3) + (o0 & 7);
    float wx0[4], wx1[4];
#pragma unroll
    for (int reg = 0; reg < 4; ++reg){
      wx0[reg] = (float)WxT[o0 + reg];
      wx1[reg] = (float)WxT[64 + o0 + reg];
    }
    float vA[4], vB[4];
#pragma unroll
    for (int reg = 0; reg < 4; ++reg){
      vA[reg] = accA[mt][reg] + wx0[reg]*dA0 + wx1[reg]*dA1;
      vB[reg] = accB[mt][reg] + wx0[reg]*dB0 + wx1[reg]*dB1;
    }
    v4h hA, hB;
    *(v2h*)&hA       = srelu_pk(vA[0], vA[1]);
    *((v2h*)&hA + 1) = srelu_pk(vA[2], vA[3]);
    *(v2h*)&hB       = srelu_pk(vB[0], vB[1]);
    *((v2h*)&hB + 1) = srelu_pk(vB[2], vB[3]);
    *(v4h*)(zoutA + lm*64 + off) = hA;
    *(v4h*)(zoutB + lm*64 + off) = hB;
  }
}

__device__ __forceinline__ void vbwd2(const _Float16* ginA, _Float16* zioA,
    const _Float16* ginB, _Float16* zioB,
    const _Float16* __restrict__ WT, int lm, int q)
{
  v4f accA[4], accB[4];
#pragma unroll
  for (int mt = 0; mt < 4; ++mt){
    accA[mt] = (v4f){0.f,0.f,0.f,0.f};
    accB[mt] = (v4f){0.f,0.f,0.f,0.f};
  }
  const int rs = lm & 7;
#pragma unroll
  for (int kt = 0; kt < 2; ++kt){
    const int sw = (((kt*4 + q) ^ rs) << 3);
    v8h BA = *(const v8h*)(ginA + lm*64 + sw);
    v8h BB = *(const v8h*)(ginB + lm*64 + sw);
#pragma unroll
    for (int mt = 0; mt < 4; ++mt){
      v8h A = *(const v8h*)(WT + (mt*16 + lm)*64 + kt*32 + q*8);
      accA[mt] = __builtin_amdgcn_mfma_f32_16x16x32_f16(A, BA, accA[mt], 0,0,0);
      accB[mt] = __builtin_amdgcn_mfma_f32_16x16x32_f16(A, BB, accB[mt], 0,0,0);
    }
  }
#pragma unroll
  for (int mt = 0; mt < 4; ++mt){
    const int k0 = mt*16 + q*4;
    const int off = (((k0 >> 3) ^ rs) << 3) + (k0 & 7);
    _Float16* pA = zioA + lm*64 + off;
    _Float16* pB = zioB + lm*64 + off;
    v4h zA = *(const v4h*)pA;
    v4h zB = *(const v4h*)pB;
    float sA0 = accA[mt][0] * sreluD_from_z((float)zA[0]);
    float sA1 = accA[mt][1] * sreluD_from_z((float)zA[1]);
    float sA2 = accA[mt][2] * sreluD_from_z((float)zA[2]);
    float sA3 = accA[mt][3] * sreluD_from_z((float)zA[3]);
    float sB0 = accB[mt][0] * sreluD_from_z((float)zB[0]);
    float sB1 = accB[mt][1] * sreluD_from_z((float)zB[1]);
    float sB2 = accB[mt][2] * sreluD_from_z((float)zB[2]);
    float sB3 = accB[mt][3] * sreluD_from_z((float)zB[3]);
    v4h gA, gB;
    *(v2h*)&gA       = cvt_pk(sA0, sA1);
    *((v2h*)&gA + 1) = cvt_pk(sA2, sA3);
    *(v2h*)&gB       = cvt_pk(sB0, sB1);
    *((v2h*)&gB + 1) = cvt_pk(sB2, sB3);
    *(v4h*)pA = gA;
    *(v4h*)pB = gB;
  }
}

__device__ __forceinline__ void vnet_body2(int b, char* smem,
  const float* __restrict__ X, const float* __restrict__ Xst,
  const float* __restrict__ Vfx)
{
  const int t  = threadIdx.x;
  const int w  = t >> 6;
  const int l  = t & 63;
  const int lm = l & 15;
  const int q  = l >> 4;
  const int rs = lm & 7;

  _Float16* const ZA1 = (_Float16*)(smem + w*12288);   // 6 x 2 KB per wave
  _Float16* const ZA2 = ZA1 + 1024;
  _Float16* const ZA3 = ZA1 + 2048;
  _Float16* const ZB1 = ZA1 + 3072;
  _Float16* const ZB2 = ZA1 + 4096;
  _Float16* const ZB3 = ZA1 + 5120;

  const int rowA = b*128 + w*32 + lm;
  const int rowB = rowA + 16;
  const int rcA = rowA < NPTS ? rowA : NPTS-1;
  const int rcB = rowB < NPTS ? rowB : NPTS-1;
  const float2 xA = *(const float2*)(X   + rcA*2);
  const float2 sA = *(const float2*)(Xst + rcA*2);
  const float2 xB = *(const float2*)(X   + rcB*2);
  const float2 sB = *(const float2*)(Xst + rcB*2);
  const float dA0 = xA.x - sA.x, dA1 = xA.y - sA.y;
  const float dB0 = xB.x - sB.x, dB1 = xB.y - sB.y;
  const float vfx0 = Vfx[0], vfx1 = Vfx[1];

  // z1 for both pipelines (shared weight regs)
  {
    v8h w0a = *(const v8h*)(g_w16 + OFF_VL1T + q*16);
    v8h w0b = *(const v8h*)(g_w16 + OFF_VL1T + q*16 + 8);
    v8h w1a = *(const v8h*)(g_w16 + OFF_VL1T + 64 + q*16);
    v8h w1b = *(const v8h*)(g_w16 + OFF_VL1T + 64 + q*16 + 8);
    v8h zaA, zbA, zaB, zbB;
#pragma unroll
    for (int j2 = 0; j2 < 4; ++j2){
      float a0 = (float)w0a[2*j2  ], a1 = (float)w0a[2*j2+1];
      float b0 = (float)w0b[2*j2  ], b1 = (float)w0b[2*j2+1];
      float c0 = (float)w1a[2*j2  ], c1 = (float)w1a[2*j2+1];
      float e0 = (float)w1b[2*j2  ], e1 = (float)w1b[2*j2+1];
      ((v2h*)&zaA)[j2] = srelu_pk(fmaf(dA0,a0,dA1*c0), fmaf(dA0,a1,dA1*c1));
      ((v2h*)&zbA)[j2] = srelu_pk(fmaf(dA0,b0,dA1*e0), fmaf(dA0,b1,dA1*e1));
      ((v2h*)&zaB)[j2] = srelu_pk(fmaf(dB0,a0,dB1*c0), fmaf(dB0,a1,dB1*c1));
      ((v2h*)&zbB)[j2] = srelu_pk(fmaf(dB0,b0,dB1*e0), fmaf(dB0,b1,dB1*e1));
    }
    const int s0 = (((q*2    ) ^ rs) << 3);
    const int s1 = (((q*2 + 1) ^ rs) << 3);
    *(v8h*)(ZA1 + lm*64 + s0) = zaA;
    *(v8h*)(ZA1 + lm*64 + s1) = zbA;
    *(v8h*)(ZB1 + lm*64 + s0) = zaB;
    *(v8h*)(ZB1 + lm*64 + s1) = zbB;
  }

  // z2, z3 (two pipelines, shared A)
  vfwd2(ZA1, ZA2, ZB1, ZB2, g_w16 + OFF_V2Z, g_w16 + OFF_V2XT,
        dA0, dA1, dB0, dB1, lm, q);
  vfwd2(ZA2, ZA3, ZB2, ZB3, g_w16 + OFF_V3Z, g_w16 + OFF_V3XT,
        dA0, dA1, dB0, dB1, lm, q);

  // zf head for both (A row 0 = Vfz, shared)
  float VVrA, sfA, VVrB, sfB;
  {
    v4f aSA = (v4f){0.f,0.f,0.f,0.f};
    v4f aSB = (v4f){0.f,0.f,0.f,0.f};
#pragma unroll
    for (int kt = 0; kt < 2; ++kt){
      const int sw = (((kt*4 + q) ^ rs) << 3);
      v8h A  = *(const v8h*)(g_w16 + OFF_VFZ + lm*64 + kt*32 + q*8);
      v8h BA = *(const v8h*)(ZA3 + lm*64 + sw);
      v8h BB = *(const v8h*)(ZB3 + lm*64 + sw);
      aSA = __builtin_amdgcn_mfma_f32_16x16x32_f16(A, BA, aSA, 0,0,0);
      aSB = __builtin_amdgcn_mfma_f32_16x16x32_f16(A, BB, aSB, 0,0,0);
    }
    const float afA = fmaf(vfx0, dA0, fmaf(vfx1, dA1, aSA[0]));
    const float zfA = srelu(afA);
    VVrA = srelu(zfA) + 0.01f * fmaf(dA0, dA0, dA1*dA1);
    sfA  = sreluD(zfA) * sreluD(afA);
    const float afB = fmaf(vfx0, dB0, fmaf(vfx1, dB1, aSB[0]));
    const float zfB = srelu(afB);
    VVrB = srelu(zfB) + 0.01f * fmaf(dB0, dB0, dB1*dB1);
    sfB  = sreluD(zfB) * sreluD(afB);
  }

  // u3 = Vfz * srelu'(a3) for both (sf deferred)
#pragma unroll
  for (int cc = 0; cc < 2; ++cc){
    const int c = q*2 + cc;
    const int sw = ((c ^ rs) << 3);
    v8h vf = *(const v8h*)(g_w16 + OFF_VFZ + c*8);
    _Float16* pA = ZA3 + lm*64 + sw;
    _Float16* pB = ZB3 + lm*64 + sw;
    v8h zA = *(const v8h*)pA;
    v8h zB = *(const v8h*)pB;
    v8h uA, uB;
#pragma unroll
    for (int j2 = 0; j2 < 4; ++j2){
      float a0 = (float)vf[2*j2  ] * sreluD_from_z((float)zA[2*j2  ]);
      float a1 = (float)vf[2*j2+1] * sreluD_from_z((float)zA[2*j2+1]);
      float b0 = (float)vf[2*j2  ] * sreluD_from_z((float)zB[2*j2  ]);
      float b1 = (float)vf[2*j2+1] * sreluD_from_z((float)zB[2*j2+1]);
      ((v2h*)&uA)[j2] = cvt_pk(a0, a1);
      ((v2h*)&uB)[j2] = cvt_pk(b0, b1);
    }
    *(v8h*)pA = uA;
    *(v8h*)pB = uB;
  }

  // backward (both pipelines, shared A)
  vbwd2(ZA3, ZA2, ZB3, ZB2, g_w16 + OFF_V3ZT, lm, q);
  vbwd2(ZA2, ZA1, ZB2, ZB1, g_w16 + OFF_V2ZT, lm, q);

  // gradV for both (A rows 0/1 = Wx^T, shared); apply sf once
  float g0A, g1A, g0B, g1B;
  {
    v4f aGA = (v4f){0.f,0.f,0.f,0.f};
    v4f aGB = (v4f){0.f,0.f,0.f,0.f};
    const _Float16* ZsA[3] = {ZA1, ZA2, ZA3};
    const _Float16* ZsB[3] = {ZB1, ZB2, ZB3};
    const int       Ws[3]  = {OFF_VL1T, OFF_V2XT, OFF_V3XT};
#pragma unroll
    for (int li = 0; li < 3; ++li){
#pragma unroll
      for (int kt = 0; kt < 2; ++kt){
        const int sw = (((kt*4 + q) ^ rs) << 3);
        v8h A  = *(const v8h*)(g_w16 + Ws[li] + lm*64 + kt*32 + q*8);
        v8h BA = *(const v8h*)(ZsA[li] + lm*64 + sw);
        v8h BB = *(const v8h*)(ZsB[li] + lm*64 + sw);
        aGA = __builtin_amdgcn_mfma_f32_16x16x32_f16(A, BA, aGA, 0,0,0);
        aGB = __builtin_amdgcn_mfma_f32_16x16x32_f16(A, BB, aGB, 0,0,0);
      }
    }
    g0A = fmaf(0.02f, dA0, sfA * (vfx0 + aGA[0]));
    g1A = fmaf(0.02f, dA1, sfA * (vfx1 + aGA[1]));
    g0B = fmaf(0.02f, dB0, sfB * (vfx0 + aGB[0]));
    g1B = fmaf(0.02f, dB1, sfB * (vfx1 + aGB[1]));
  }

  // write (g0, g1, V) for the combine kernel (q==0 lanes)
  if (q == 0){
    if (rowA < NPTS) g_grad[rowA] = make_float4(g0A, g1A, VVrA, 0.f);
    if (rowB < NPTS) g_grad[rowB] = make_float4(g0B, g1B, VVrB, 0.f);
  }
}

// ================= fused heterogeneous kernel =================
__global__ __launch_bounds__(256, 4) void fused_kernel(
  const float* __restrict__ X, const float* __restrict__ Xst,
  const float* __restrict__ Vfx,
  const float* __restrict__ f1b, const float* __restrict__ f2b,
  const float* __restrict__ f3b, const float* __restrict__ f4b,
  const float* __restrict__ f5b, const float* __restrict__ ffb)
{
  __shared__ __align__(16) char smem[49152];   // fhat 32 KB | vnet 48 KB
  const int g = blockIdx.x;
  if ((g & 1) == 0){
    fhat_body(g >> 1, (_Float16*)smem, X, f1b, f2b, f3b, f4b, f5b, ffb);
  } else {
    vnet_body2(g >> 1, smem, X, Xst, Vfx);
  }
}

// ================= combine epilogue (2 rows/thread, ~16 MB) =================
__global__ __launch_bounds__(256) void combine_kernel(float* __restrict__ out)
{
  const int idx = blockIdx.x * 256 + threadIdx.x;
  const int i0 = idx * 2;
  if (i0 >= NPTS) return;
  const float4 fh2 = *(const float4*)(g_fh + i0*2);   // rows i0, i0+1
  const float4 ga = g_grad[i0];
  const float4 gb = g_grad[i0 + 1];
  float4 o;
  {
    const float Vn  = fmaf(ga.x, ga.x, ga.y*ga.y);
    const float num = fmaf(0.1f, ga.z, fmaf(fh2.x, ga.x, fh2.y*ga.y));
    const float fm  = fmaxf(num, 0.f) / (Vn + 1e-10f);
    o.x = fmaf(-ga.x, fm, fh2.x);
    o.y = fmaf(-ga.y, fm, fh2.y);
  }
  {
    const float Vn  = fmaf(gb.x, gb.x, gb.y*gb.y);
    const float num = fmaf(0.1f, gb.z, fmaf(fh2.z, gb.x, fh2.w*gb.y));
    const float fm  = fmaxf(num, 0.f) / (Vn + 1e-10f);
    o.z = fmaf(-gb.x, fm, fh2.z);
    o.w = fmaf(-gb.y, fm, fh2.w);
  }
  *(float4*)(out + i0*2) = o;
}

extern "C" void kernel_launch(void* const* d_in, const int* in_sizes, int n_in,
                              void* d_out, int out_size, void* d_ws, size_t ws_size,
                              hipStream_t stream)
{
  (void)d_ws; (void)ws_size; (void)n_in; (void)in_sizes; (void)out_size;
  const float* X   = (const float*)d_in[0];
  const float* Xst = (const float*)d_in[1];
  const float* Vl1 = (const float*)d_in[2];
  const float* V2x = (const float*)d_in[3];
  const float* V2z = (const float*)d_in[4];
  const float* V3x = (const float*)d_in[5];
  const float* V3z = (const float*)d_in[6];
  const float* Vfx = (const float*)d_in[7];
  const float* Vfz = (const float*)d_in[8];
  const float* f1w = (const float*)d_in[9];
  const float* f1b = (const float*)d_in[10];
  const float* f2w = (const float*)d_in[11];
  const float* f2b = (const float*)d_in[12];
  const float* f3w = (const float*)d_in[13];
  const float* f3b = (const float*)d_in[14];
  const float* f4w = (const float*)d_in[15];
  const float* f4b = (const float*)d_in[16];
  const float* f5w = (const float*)d_in[17];
  const float* f5b = (const float*)d_in[18];
  const float* ffw = (const float*)d_in[19];
  const float* ffb = (const float*)d_in[20];

  prep_kernel<<<(W16_TOTAL + 255)/256, 256, 0, stream>>>(
      f2w, f3w, f4w, f5w, V2z, V3z, Vl1, V2x, V3x, Vfz, ffw, f1w);
  fused_kernel<<<FUSED_GRID, 256, 0, stream>>>(
      X, Xst, Vfx, f1b, f2b, f3b, f4b, f5b, ffb);
  combine_kernel<<<(NPTS/2 + 255)/256, 256, 0, stream>>>((float*)d_out);
}